// Round 1
// 81.893 us; speedup vs baseline: 1.0242x; 1.0242x over previous
//
#include <hip/hip_runtime.h>

// out[b,co,h,w] = sum_ci dq( conv3x3(x[b,ci], W[ci,co]) + b[ci,co] )
// Bit-exactness contract (verified R3 absmax==0, R4..R10 absmax=1.4e-6):
//   per-pixel conv = sequential fma over k=(kh*3+kw) ascending, seeded from 0;
//   bias after as plain f32 add; t = y * (float)(15/9); rintf (half-even);
//   dequant+sum: fma(q, 0.6f, acc), ci ascending. Packed v_pk_fma_f32 is IEEE
//   per 32-bit half -> identical bits per pixel.
// R11: supply WAVES, not just work-per-wave. R4..R9 occupancy levers were
// neutral because the grid only had 784 blocks = 3136 waves = 3.06/SIMD;
// VALUBusy ~47% means each wave is half-stalled with nothing to cover it.
// Split co across blocks: COG 8->4, grid z = 8 batches x 2 co-halves ->
// 1568 blocks = 6272 waves ~ 6.1/SIMD. acc drops 16->8 VGPRs so
// launch_bounds(256,6) (VGPR cap ~85) allows 6 blocks/CU: 1536/1568 blocks
// resident at once. x staged twice overall (+6.4MB HBM, L2/L3-absorbed).
// Math order per (ci,co,px) untouched -> same bits.

typedef float v2f __attribute__((ext_vector_type(2)));

constexpr int B_    = 8;
constexpr int CIN   = 16;
constexpr int COUT  = 32;
constexpr int H_    = 112;
constexpr int W_    = 112;
constexpr int TW    = 16;            // tile width  (112 = 7*16)
constexpr int TH    = 8;             // tile height (112 = 14*8)
constexpr int HW_   = TW + 2;        // halo width 18
constexpr int HH_   = TH + 2;        // halo height 10
constexpr int LDSW  = 20;            // even row stride (b64 alignment) + pad
constexpr int COG   = 4;             // co per wave (co-half split across blocks)

__global__ __launch_bounds__(256, 6)
void conv_quant_sum_kernel(const float* __restrict__ x,
                           const float* __restrict__ w,
                           const float* __restrict__ bias,
                           float* __restrict__ out)
{
#pragma clang fp contract(off)
    const float QS = (float)(15.0 / 9.0);   // 1.66666663f
    const float DQ = 0.6f;                  // post-round dequant multiplier

    __shared__ float xs[CIN][HH_][LDSW];    // 16*10*20*4 = 12.8 KB

    const int t    = threadIdx.x;
    const int lane = t & 63;
    const int tx   = lane & 7;              // pair col: pixels 2tx, 2tx+1
    const int ty   = lane >> 3;             // row 0..7
    const int wid  = __builtin_amdgcn_readfirstlane(t >> 6);

    const int tile_x = blockIdx.x * TW;
    const int tile_y = blockIdx.y * TH;
    const int bz     = blockIdx.z;
    const int b      = bz & 7;              // batch
    const int coh    = bz >> 3;             // co half (0 or 1)
    const int cog    = coh * 16 + wid * COG;

    // ---- stage x halo tile (18x10 per ci, zero-padded at borders) ----
    const float* xb = x + (size_t)b * CIN * H_ * W_;
    for (int idx = t; idx < CIN * HH_ * HW_; idx += 256) {
        int ci  = idx / (HH_ * HW_);
        int rem = idx - ci * (HH_ * HW_);
        int r   = rem / HW_;
        int c   = rem - r * HW_;
        int gh  = tile_y + r - 1;
        int gw  = tile_x + c - 1;
        float v = 0.0f;
        if ((unsigned)gh < (unsigned)H_ && (unsigned)gw < (unsigned)W_)
            v = xb[ci * H_ * W_ + gh * W_ + gw];
        xs[ci][r][c] = v;
    }
    __syncthreads();

    v2f acc[COG];
#pragma unroll
    for (int co = 0; co < COG; ++co) acc[co] = v2f{0.0f, 0.0f};

    for (int ci = 0; ci < CIN; ++ci) {
        // two 3x3 windows from halo cols 2tx..2tx+3, rows ty..ty+2
        v2f xw[3][3];
#pragma unroll
        for (int r = 0; r < 3; ++r) {
            const float* row = &xs[ci][ty + r][2 * tx];
            v2f p0 = *reinterpret_cast<const v2f*>(row);      // b64, 8B-aligned
            v2f p1 = *reinterpret_cast<const v2f*>(row + 2);  // b64
            xw[r][0] = p0;
            xw[r][1] = v2f{p0.y, p1.x};
            xw[r][2] = p1;
        }

        const float* wc = w + (ci * COUT + cog) * 9;   // wave-uniform scalar
        const float* bc = bias + ci * COUT + cog;
#pragma unroll
        for (int co = 0; co < COG; ++co) {
            v2f s = v2f{0.0f, 0.0f};                   // conv seeded from 0
#pragma unroll
            for (int k = 0; k < 9; ++k) {
                float wv = wc[co * 9 + k];
                s = __builtin_elementwise_fma(xw[k / 3][k % 3], v2f{wv, wv}, s);
            }
            float bv = bc[co];
            v2f y  = s + v2f{bv, bv};                  // bias: pk_add
            v2f tq = y * v2f{QS, QS};                  // pk_mul
            v2f q;
            q.x = rintf(tq.x);                         // v_rndne_f32 half-even
            q.y = rintf(tq.y);
            acc[co] = __builtin_elementwise_fma(q, v2f{DQ, DQ}, acc[co]);
        }
    }

    // ---- store: 2 adjacent pixels -> 8B-aligned dwordx2 ----
    float* ob = out + ((size_t)b * COUT + cog) * H_ * W_;
    const int oh = tile_y + ty;
    const int ow = tile_x + 2 * tx;
#pragma unroll
    for (int co = 0; co < COG; ++co)
        *reinterpret_cast<v2f*>(ob + co * H_ * W_ + oh * W_ + ow) = acc[co];
}

extern "C" void kernel_launch(void* const* d_in, const int* in_sizes, int n_in,
                              void* d_out, int out_size, void* d_ws, size_t ws_size,
                              hipStream_t stream)
{
    const float* x    = (const float*)d_in[0];
    const float* w    = (const float*)d_in[1];
    const float* bias = (const float*)d_in[2];
    float* out        = (float*)d_out;

    dim3 grid(W_ / TW, H_ / TH, B_ * 2);   // (7, 14, 16) = 1568 blocks
    dim3 block(256);
    conv_quant_sum_kernel<<<grid, block, 0, stream>>>(x, w, bias, out);
}